// Round 1
// baseline (4100.948 us; speedup 1.0000x reference)
//
#include <hip/hip_runtime.h>
#include <cmath>

typedef _Float16 f16;
typedef _Float16 half8 __attribute__((ext_vector_type(8)));
typedef float f32x4 __attribute__((ext_vector_type(4)));

// ---------------- utility kernels ----------------

__global__ void zero_stats(float* p) { p[blockIdx.x * 256 + threadIdx.x] = 0.f; }

// W (K x N fp32, row-major) -> Wt (N x K f16, row-major)
__global__ void wcvt(const float* __restrict__ W, f16* __restrict__ Wt, int K, int N) {
    int i = blockIdx.x * 256 + threadIdx.x;
    if (i < K * N) {
        int k = i / N, n = i - k * N;
        Wt[(size_t)n * K + k] = (f16)W[i];
    }
}

// lin2_w (256 x 47 fp32) -> lin2t (47 x 256 fp32)
__global__ void lin2t_k(const float* __restrict__ W, float* __restrict__ Wt) {
    int i = blockIdx.x * 256 + threadIdx.x;
    if (i < 256 * 47) {
        int k = i / 47, j = i - k * 47;
        Wt[(size_t)j * 256 + k] = W[i];
    }
}

// h0 = x[:nt] (fp32 source)
__global__ void copy_f32(const float* __restrict__ x, float* __restrict__ h0, int n4) {
    int i = blockIdx.x * 256 + threadIdx.x;
    if (i < n4) ((f32x4*)h0)[i] = ((const f32x4*)x)[i];
}

// h0 = x[:nt] (f16 source -> fp32)
__global__ void cvt_f16_f32(const f16* __restrict__ x, float* __restrict__ h0, int n8) {
    int i = blockIdx.x * 256 + threadIdx.x;
    if (i < n8) {
        half8 v = ((const half8*)x)[i];
#pragma unroll
        for (int j = 0; j < 8; ++j) h0[(size_t)i * 8 + j] = (float)v[j];
    }
}

__device__ __forceinline__ void atomAddF(float* p, float v) { unsafeAtomicAdd(p, v); }

// din = 128, fp32 source. 32 threads per edge, 4 ch each.
__global__ void scatter_add_f32(const float* __restrict__ x, const int* __restrict__ src,
                                const int* __restrict__ tgt, float* __restrict__ h0, int E) {
    int t = blockIdx.x * 256 + threadIdx.x;
    int e = t >> 5;
    if (e >= E) return;
    int c4 = (t & 31) * 4;
    const f32x4 v = *(const f32x4*)(x + (size_t)src[e] * 128 + c4);
    float* hp = h0 + (size_t)tgt[e] * 128 + c4;
    atomAddF(hp + 0, v[0]);
    atomAddF(hp + 1, v[1]);
    atomAddF(hp + 2, v[2]);
    atomAddF(hp + 3, v[3]);
}

// din = 256, f16 source. 32 threads per edge, 8 ch each.
__global__ void scatter_add_f16(const f16* __restrict__ x, const int* __restrict__ src,
                                const int* __restrict__ tgt, float* __restrict__ h0, int E) {
    int t = blockIdx.x * 256 + threadIdx.x;
    int e = t >> 5;
    if (e >= E) return;
    int c8 = (t & 31) * 8;
    const half8 v = *(const half8*)(x + (size_t)src[e] * 256 + c8);
    float* hp = h0 + (size_t)tgt[e] * 256 + c8;
#pragma unroll
    for (int i = 0; i < 8; ++i) atomAddF(hp + i, (float)v[i]);
}

// ---------------- GEMM: C(MxN f16) = A(MxK) @ Bt^T(NxK f16) + bias, opt relu ----------------
// M % 64 == 0, N % 64 == 0, K % 32 == 0 guaranteed by problem sizes.
template <typename AT, bool RELU>
__global__ __launch_bounds__(256) void gemm_bt(const AT* __restrict__ A, const f16* __restrict__ Bt,
                                               const float* __restrict__ bias, f16* __restrict__ C,
                                               int M, int N, int K) {
    constexpr int BM = 64, BN = 64, BK = 32, LP = 40;  // LDS pitch (halves): 80B, 16B-aligned
    __shared__ f16 sA[BM * LP];
    __shared__ f16 sB[BN * LP];
    const int tid = threadIdx.x;
    const int wave = tid >> 6, lane = tid & 63;
    const int quad = lane >> 4, l16 = lane & 15;
    const int wr = (wave & 1) * 32, wc = (wave >> 1) * 32;
    const int row0 = blockIdx.x * BM, col0 = blockIdx.y * BN;
    const int srow = tid >> 2, soff = (tid & 3) * 8;

    f32x4 acc[2][2] = {};

    for (int k0 = 0; k0 < K; k0 += BK) {
        __syncthreads();
        // stage A tile (64 x 32)
        {
            const AT* ap = A + (size_t)(row0 + srow) * K + (k0 + soff);
            half8 v;
            if constexpr (sizeof(AT) == 2) {
                v = *(const half8*)ap;
            } else {
                const f32x4 v0 = *(const f32x4*)ap;
                const f32x4 v1 = *(const f32x4*)(ap + 4);
#pragma unroll
                for (int j = 0; j < 4; ++j) { v[j] = (f16)v0[j]; v[4 + j] = (f16)v1[j]; }
            }
            *(half8*)&sA[srow * LP + soff] = v;
        }
        // stage B tile (64 cols x 32 k), Bt is N x K
        {
            const f16* bp = Bt + (size_t)(col0 + srow) * K + (k0 + soff);
            *(half8*)&sB[srow * LP + soff] = *(const half8*)bp;
        }
        __syncthreads();
        half8 af[2], bf[2];
#pragma unroll
        for (int r = 0; r < 2; ++r) af[r] = *(const half8*)&sA[(wr + r * 16 + l16) * LP + quad * 8];
#pragma unroll
        for (int c = 0; c < 2; ++c) bf[c] = *(const half8*)&sB[(wc + c * 16 + l16) * LP + quad * 8];
#pragma unroll
        for (int r = 0; r < 2; ++r)
#pragma unroll
            for (int c = 0; c < 2; ++c)
                acc[r][c] = __builtin_amdgcn_mfma_f32_16x16x32_f16(af[r], bf[c], acc[r][c], 0, 0, 0);
    }

    // epilogue: C/D layout col = lane&15, row = quad*4 + reg
#pragma unroll
    for (int c = 0; c < 2; ++c) {
        const int gcol = col0 + wc + c * 16 + l16;
        const float b = bias[gcol];
#pragma unroll
        for (int r = 0; r < 2; ++r) {
#pragma unroll
            for (int i = 0; i < 4; ++i) {
                const int grow = row0 + wr + r * 16 + quad * 4 + i;
                float v = acc[r][c][i] + b;
                if (RELU) v = fmaxf(v, 0.f);
                C[(size_t)grow * N + gcol] = (f16)v;
            }
        }
    }
}

// ---------------- BN ----------------

// column sums over h1 (nt x 256 f16); block = 256 threads (one per column), 256 rows per block
__global__ void colstats(const f16* __restrict__ h1, int nt, float* __restrict__ colsum,
                         float* __restrict__ colsumsq) {
    const int c = threadIdx.x;
    const int r0 = blockIdx.x * 256;
    const int rend = min(r0 + 256, nt);
    float s = 0.f, ss = 0.f;
    for (int r = r0; r < rend; ++r) {
        float v = (float)h1[(size_t)r * 256 + c];
        s += v;
        ss += v * v;
    }
    atomAddF(&colsum[c], s);
    atomAddF(&colsumsq[c], ss);
}

__global__ void bn_finalize(const float* __restrict__ colsum, const float* __restrict__ colsumsq,
                            const float* __restrict__ g, const float* __restrict__ be, float nt_inv,
                            float* __restrict__ scale, float* __restrict__ shift) {
    int c = threadIdx.x;
    float mu = colsum[c] * nt_inv;
    float var = colsumsq[c] * nt_inv - mu * mu;
    float sc = g[c] * rsqrtf(var + 1e-5f);
    scale[c] = sc;
    shift[c] = be[c] - mu * sc;
}

// in-place: h1 = relu(h1*scale + shift); total8 = nt*256/8
__global__ void bn_apply(f16* __restrict__ h, int total8, const float* __restrict__ scale,
                         const float* __restrict__ shift) {
    int i = blockIdx.x * 256 + threadIdx.x;
    if (i >= total8) return;
    size_t base = (size_t)i * 8;
    int c = (int)(base & 255);
    half8 v = *(half8*)(h + base);
#pragma unroll
    for (int j = 0; j < 8; ++j) {
        float f = (float)v[j] * scale[c + j] + shift[c + j];
        v[j] = (f16)fmaxf(f, 0.f);
    }
    *(half8*)(h + base) = v;
}

// ---------------- head: logits + log_softmax ----------------
// T: 1024 x 256 f16; w2t: 47 x 256 fp32; out: 1024 x 47 fp32. One 64-thread block per row.
__global__ void head2(const f16* __restrict__ T, const float* __restrict__ w2t,
                      const float* __restrict__ b2, float* __restrict__ out, int rows) {
    const int row = blockIdx.x;
    const int lane = threadIdx.x;
    __shared__ float tr[256];
    for (int i = lane; i < 256; i += 64) tr[i] = (float)T[(size_t)row * 256 + i];
    __syncthreads();
    float d = -1e30f;
    if (lane < 47) {
        const float* wr = w2t + (size_t)lane * 256;
        float dot = 0.f;
        for (int k = 0; k < 256; k += 4) {
            dot += tr[k] * wr[k] + tr[k + 1] * wr[k + 1] + tr[k + 2] * wr[k + 2] +
                   tr[k + 3] * wr[k + 3];
        }
        d = dot + b2[lane];
    }
    float m = d;
    for (int off = 32; off; off >>= 1) m = fmaxf(m, __shfl_xor(m, off));
    float e = (lane < 47) ? expf(d - m) : 0.f;
    float s = e;
    for (int off = 32; off; off >>= 1) s += __shfl_xor(s, off);
    if (lane < 47) out[(size_t)row * 47 + lane] = d - m - logf(s);
}

// ---------------- launch ----------------

extern "C" void kernel_launch(void* const* d_in, const int* in_sizes, int n_in, void* d_out,
                              int out_size, void* d_ws, size_t ws_size, hipStream_t stream) {
    const float* x0 = (const float*)d_in[0];
    const int* ei[3] = {(const int*)d_in[1], (const int*)d_in[2], (const int*)d_in[3]};
    const int E[3] = {in_sizes[1] / 2, in_sizes[2] / 2, in_sizes[3] / 2};
    const float* c_w1[3] = {(const float*)d_in[4], (const float*)d_in[10], (const float*)d_in[16]};
    const float* c_b1[3] = {(const float*)d_in[5], (const float*)d_in[11], (const float*)d_in[17]};
    const float* c_g[3] = {(const float*)d_in[6], (const float*)d_in[12], (const float*)d_in[18]};
    const float* c_be[3] = {(const float*)d_in[7], (const float*)d_in[13], (const float*)d_in[19]};
    const float* c_w2[3] = {(const float*)d_in[8], (const float*)d_in[14], (const float*)d_in[20]};
    const float* c_b2[3] = {(const float*)d_in[9], (const float*)d_in[15], (const float*)d_in[21]};
    const float* lin1_w = (const float*)d_in[22];
    const float* lin1_b = (const float*)d_in[23];
    const float* lin2_w = (const float*)d_in[24];
    const float* lin2_b = (const float*)d_in[25];
    float* out = (float*)d_out;

    const int NT[3] = {123904, 11264, 1024};

    char* base = (char*)d_ws;
    size_t off = 0;
    auto take = [&](size_t bytes) -> char* {
        char* p = base + off;
        off = (off + bytes + 255) & ~(size_t)255;
        return p;
    };
    f16* w1t[3];
    w1t[0] = (f16*)take((size_t)256 * 128 * sizeof(f16));
    w1t[1] = (f16*)take((size_t)256 * 256 * sizeof(f16));
    w1t[2] = (f16*)take((size_t)256 * 256 * sizeof(f16));
    f16* w2t[3];
    for (int i = 0; i < 3; ++i) w2t[i] = (f16*)take((size_t)256 * 256 * sizeof(f16));
    f16* lin1t = (f16*)take((size_t)256 * 256 * sizeof(f16));
    float* lin2t_ = (float*)take((size_t)47 * 256 * sizeof(float));
    float* stats = (float*)take(1024 * sizeof(float));
    float* h0 = (float*)take((size_t)123904 * 128 * sizeof(float));
    f16* h1 = (f16*)take((size_t)123904 * 256 * sizeof(f16));
    f16* X1 = (f16*)take((size_t)123904 * 256 * sizeof(f16));
    f16* X2 = (f16*)take((size_t)11264 * 256 * sizeof(f16));
    f16* X3 = (f16*)take((size_t)1024 * 256 * sizeof(f16));
    f16* T = (f16*)take((size_t)1024 * 256 * sizeof(f16));
    (void)ws_size;
    (void)out_size;
    (void)n_in;

    // weight conversion (tiny)
    wcvt<<<(128 * 256 + 255) / 256, 256, 0, stream>>>(c_w1[0], w1t[0], 128, 256);
    wcvt<<<256, 256, 0, stream>>>(c_w1[1], w1t[1], 256, 256);
    wcvt<<<256, 256, 0, stream>>>(c_w1[2], w1t[2], 256, 256);
    for (int i = 0; i < 3; ++i) wcvt<<<256, 256, 0, stream>>>(c_w2[i], w2t[i], 256, 256);
    wcvt<<<256, 256, 0, stream>>>(lin1_w, lin1t, 256, 256);
    lin2t_k<<<47, 256, 0, stream>>>(lin2_w, lin2t_);

    auto run_post = [&](f16* h1p, const f16* w1tp, const float* b1, const float* g,
                        const float* be, const f16* w2tp, const float* b2, f16* Xout, int nt,
                        int K1) {
        gemm_bt<float, false><<<dim3(nt / 64, 4), 256, 0, stream>>>(h0, w1tp, b1, h1p, nt, 256, K1);
        zero_stats<<<2, 256, 0, stream>>>(stats);
        colstats<<<(nt + 255) / 256, 256, 0, stream>>>(h1p, nt, stats, stats + 256);
        bn_finalize<<<1, 256, 0, stream>>>(stats, stats + 256, g, be, 1.0f / nt, stats + 512,
                                           stats + 768);
        bn_apply<<<(nt * 256 / 8 + 255) / 256, 256, 0, stream>>>(h1p, nt * 256 / 8, stats + 512,
                                                                 stats + 768);
        gemm_bt<f16, true><<<dim3(nt / 64, 4), 256, 0, stream>>>(h1p, w2tp, b2, Xout, nt, 256, 256);
    };

    // ---- layer 0 (x: fp32, din=128) ----
    {
        const int nt = NT[0];
        copy_f32<<<(nt * 128 / 4 + 255) / 256, 256, 0, stream>>>(x0, h0, nt * 128 / 4);
        scatter_add_f32<<<(int)(((size_t)E[0] * 32 + 255) / 256), 256, 0, stream>>>(
            x0, ei[0], ei[0] + E[0], h0, E[0]);
        run_post(h1, w1t[0], c_b1[0], c_g[0], c_be[0], w2t[0], c_b2[0], X1, nt, 128);
    }
    // ---- layer 1 (x: X1 f16, din=256) ----
    {
        const int nt = NT[1];
        cvt_f16_f32<<<(nt * 256 / 8 + 255) / 256, 256, 0, stream>>>(X1, h0, nt * 256 / 8);
        scatter_add_f16<<<(int)(((size_t)E[1] * 32 + 255) / 256), 256, 0, stream>>>(
            X1, ei[1], ei[1] + E[1], h0, E[1]);
        run_post(h1, w1t[1], c_b1[1], c_g[1], c_be[1], w2t[1], c_b2[1], X2, nt, 256);
    }
    // ---- layer 2 (x: X2 f16, din=256) ----
    {
        const int nt = NT[2];
        cvt_f16_f32<<<(nt * 256 / 8 + 255) / 256, 256, 0, stream>>>(X2, h0, nt * 256 / 8);
        scatter_add_f16<<<(int)(((size_t)E[2] * 32 + 255) / 256), 256, 0, stream>>>(
            X2, ei[2], ei[2] + E[2], h0, E[2]);
        run_post(h1, w1t[2], c_b1[2], c_g[2], c_be[2], w2t[2], c_b2[2], X3, nt, 256);
    }
    // ---- head ----
    gemm_bt<f16, true><<<dim3(16, 4), 256, 0, stream>>>(X3, lin1t, lin1_b, T, 1024, 256, 256);
    head2<<<1024, 64, 0, stream>>>(T, lin2t_, lin2_b, out, 1024);
}

// Round 2
// 1449.367 us; speedup vs baseline: 2.8295x; 2.8295x over previous
//
#include <hip/hip_runtime.h>
#include <cmath>

typedef _Float16 f16;
typedef _Float16 half8 __attribute__((ext_vector_type(8)));
typedef _Float16 half4 __attribute__((ext_vector_type(4)));
typedef float f32x4 __attribute__((ext_vector_type(4)));

// ---------------- utility kernels ----------------

__global__ void zero_stats(float* p) { p[blockIdx.x * 256 + threadIdx.x] = 0.f; }

__global__ void zero_i32(int* p, int n) {
    int i = blockIdx.x * 256 + threadIdx.x;
    if (i < n) p[i] = 0;
}

// W (K x N fp32, row-major) -> Wt (N x K f16, row-major)
__global__ void wcvt(const float* __restrict__ W, f16* __restrict__ Wt, int K, int N) {
    int i = blockIdx.x * 256 + threadIdx.x;
    if (i < K * N) {
        int k = i / N, n = i - k * N;
        Wt[(size_t)n * K + k] = (f16)W[i];
    }
}

// lin2_w (256 x 47 fp32) -> lin2t (47 x 256 fp32)
__global__ void lin2t_k(const float* __restrict__ W, float* __restrict__ Wt) {
    int i = blockIdx.x * 256 + threadIdx.x;
    if (i < 256 * 47) {
        int k = i / 47, j = i - k * 47;
        Wt[(size_t)j * 256 + k] = W[i];
    }
}

__device__ __forceinline__ void atomAddF(float* p, float v) { unsafeAtomicAdd(p, v); }

// ---------------- adjacency build (capacity 64/row; Poisson(10) => P(>64) ~ 1e-26) ----------------

__global__ void fill_adj(const int* __restrict__ src, const int* __restrict__ tgt,
                         int* __restrict__ deg, int* __restrict__ adj, int E) {
    int e = blockIdx.x * 256 + threadIdx.x;
    if (e >= E) return;
    int t = tgt[e];
    int pos = atomicAdd(&deg[t], 1);
    if (pos < 64) adj[(size_t)t * 64 + pos] = src[e];
}

// ---------------- gather-based segment sum: h[t] = x[t] + sum_{s in adj[t]} x[s] ----------------

// layer 0: x fp32 (ns x 128) -> h f16 (nt x 128). One wave per target row.
__global__ void gather128(const float* __restrict__ x, const int* __restrict__ deg,
                          const int* __restrict__ adj, f16* __restrict__ h) {
    const int wave = threadIdx.x >> 6, lane = threadIdx.x & 63;
    const int row = blockIdx.x * 4 + wave;
    const int c = lane * 2;
    const float* xr = x + (size_t)row * 128 + c;
    float a0 = xr[0], a1 = xr[1];
    const int n = min(deg[row], 64);
    const int myadj = adj[(size_t)row * 64 + lane];
    for (int j = 0; j < n; ++j) {
        const int s = __shfl(myadj, j);
        const float* xs = x + (size_t)s * 128 + c;
        a0 += xs[0];
        a1 += xs[1];
    }
    f16* hp = h + (size_t)row * 128 + c;
    hp[0] = (f16)a0;
    hp[1] = (f16)a1;
}

// layers 1/2: x f16 (ns x 256) -> h f16 (nt x 256). One wave per target row.
__global__ void gather256(const f16* __restrict__ x, const int* __restrict__ deg,
                          const int* __restrict__ adj, f16* __restrict__ h) {
    const int wave = threadIdx.x >> 6, lane = threadIdx.x & 63;
    const int row = blockIdx.x * 4 + wave;
    const int c = lane * 4;
    half4 xv = *(const half4*)(x + (size_t)row * 256 + c);
    float a0 = (float)xv[0], a1 = (float)xv[1], a2 = (float)xv[2], a3 = (float)xv[3];
    const int n = min(deg[row], 64);
    const int myadj = adj[(size_t)row * 64 + lane];
    for (int j = 0; j < n; ++j) {
        const int s = __shfl(myadj, j);
        half4 v = *(const half4*)(x + (size_t)s * 256 + c);
        a0 += (float)v[0];
        a1 += (float)v[1];
        a2 += (float)v[2];
        a3 += (float)v[3];
    }
    half4 o;
    o[0] = (f16)a0;
    o[1] = (f16)a1;
    o[2] = (f16)a2;
    o[3] = (f16)a3;
    *(half4*)(h + (size_t)row * 256 + c) = o;
}

// ---------------- GEMM: C(MxN f16) = A(MxK f16) @ Bt^T(NxK f16) + bias, opt relu ----------------
template <bool RELU>
__global__ __launch_bounds__(256) void gemm_bt(const f16* __restrict__ A, const f16* __restrict__ Bt,
                                               const float* __restrict__ bias, f16* __restrict__ C,
                                               int M, int N, int K) {
    constexpr int BM = 64, BN = 64, BK = 32, LP = 40;  // LDS pitch (halves): 80B, 16B-aligned
    __shared__ f16 sA[BM * LP];
    __shared__ f16 sB[BN * LP];
    const int tid = threadIdx.x;
    const int wave = tid >> 6, lane = tid & 63;
    const int quad = lane >> 4, l16 = lane & 15;
    const int wr = (wave & 1) * 32, wc = (wave >> 1) * 32;
    const int row0 = blockIdx.x * BM, col0 = blockIdx.y * BN;
    const int srow = tid >> 2, soff = (tid & 3) * 8;

    f32x4 acc[2][2] = {};

    for (int k0 = 0; k0 < K; k0 += BK) {
        __syncthreads();
        *(half8*)&sA[srow * LP + soff] =
            *(const half8*)(A + (size_t)(row0 + srow) * K + (k0 + soff));
        *(half8*)&sB[srow * LP + soff] =
            *(const half8*)(Bt + (size_t)(col0 + srow) * K + (k0 + soff));
        __syncthreads();
        half8 af[2], bf[2];
#pragma unroll
        for (int r = 0; r < 2; ++r) af[r] = *(const half8*)&sA[(wr + r * 16 + l16) * LP + quad * 8];
#pragma unroll
        for (int c = 0; c < 2; ++c) bf[c] = *(const half8*)&sB[(wc + c * 16 + l16) * LP + quad * 8];
#pragma unroll
        for (int r = 0; r < 2; ++r)
#pragma unroll
            for (int c = 0; c < 2; ++c)
                acc[r][c] = __builtin_amdgcn_mfma_f32_16x16x32_f16(af[r], bf[c], acc[r][c], 0, 0, 0);
    }

    // epilogue: C/D layout col = lane&15, row = quad*4 + reg
#pragma unroll
    for (int c = 0; c < 2; ++c) {
        const int gcol = col0 + wc + c * 16 + l16;
        const float b = bias[gcol];
#pragma unroll
        for (int r = 0; r < 2; ++r) {
#pragma unroll
            for (int i = 0; i < 4; ++i) {
                const int grow = row0 + wr + r * 16 + quad * 4 + i;
                float v = acc[r][c][i] + b;
                if (RELU) v = fmaxf(v, 0.f);
                C[(size_t)grow * N + gcol] = (f16)v;
            }
        }
    }
}

// ---------------- BN ----------------

__global__ void colstats(const f16* __restrict__ h1, int nt, float* __restrict__ colsum,
                         float* __restrict__ colsumsq) {
    const int c = threadIdx.x;
    const int r0 = blockIdx.x * 256;
    const int rend = min(r0 + 256, nt);
    float s = 0.f, ss = 0.f;
    for (int r = r0; r < rend; ++r) {
        float v = (float)h1[(size_t)r * 256 + c];
        s += v;
        ss += v * v;
    }
    atomAddF(&colsum[c], s);
    atomAddF(&colsumsq[c], ss);
}

__global__ void bn_finalize(const float* __restrict__ colsum, const float* __restrict__ colsumsq,
                            const float* __restrict__ g, const float* __restrict__ be, float nt_inv,
                            float* __restrict__ scale, float* __restrict__ shift) {
    int c = threadIdx.x;
    float mu = colsum[c] * nt_inv;
    float var = colsumsq[c] * nt_inv - mu * mu;
    float sc = g[c] * rsqrtf(var + 1e-5f);
    scale[c] = sc;
    shift[c] = be[c] - mu * sc;
}

__global__ void bn_apply(f16* __restrict__ h, int total8, const float* __restrict__ scale,
                         const float* __restrict__ shift) {
    int i = blockIdx.x * 256 + threadIdx.x;
    if (i >= total8) return;
    size_t base = (size_t)i * 8;
    int c = (int)(base & 255);
    half8 v = *(half8*)(h + base);
#pragma unroll
    for (int j = 0; j < 8; ++j) {
        float f = (float)v[j] * scale[c + j] + shift[c + j];
        v[j] = (f16)fmaxf(f, 0.f);
    }
    *(half8*)(h + base) = v;
}

// ---------------- head: logits + log_softmax ----------------
__global__ void head2(const f16* __restrict__ T, const float* __restrict__ w2t,
                      const float* __restrict__ b2, float* __restrict__ out, int rows) {
    const int row = blockIdx.x;
    const int lane = threadIdx.x;
    __shared__ float tr[256];
    for (int i = lane; i < 256; i += 64) tr[i] = (float)T[(size_t)row * 256 + i];
    __syncthreads();
    float d = -1e30f;
    if (lane < 47) {
        const float* wr = w2t + (size_t)lane * 256;
        float dot = 0.f;
        for (int k = 0; k < 256; k += 4) {
            dot += tr[k] * wr[k] + tr[k + 1] * wr[k + 1] + tr[k + 2] * wr[k + 2] +
                   tr[k + 3] * wr[k + 3];
        }
        d = dot + b2[lane];
    }
    float m = d;
    for (int off = 32; off; off >>= 1) m = fmaxf(m, __shfl_xor(m, off));
    float e = (lane < 47) ? expf(d - m) : 0.f;
    float s = e;
    for (int off = 32; off; off >>= 1) s += __shfl_xor(s, off);
    if (lane < 47) out[(size_t)row * 47 + lane] = d - m - logf(s);
}

// ---------------- launch ----------------

extern "C" void kernel_launch(void* const* d_in, const int* in_sizes, int n_in, void* d_out,
                              int out_size, void* d_ws, size_t ws_size, hipStream_t stream) {
    const float* x0 = (const float*)d_in[0];
    const int* ei[3] = {(const int*)d_in[1], (const int*)d_in[2], (const int*)d_in[3]};
    const int E[3] = {in_sizes[1] / 2, in_sizes[2] / 2, in_sizes[3] / 2};
    const float* c_w1[3] = {(const float*)d_in[4], (const float*)d_in[10], (const float*)d_in[16]};
    const float* c_b1[3] = {(const float*)d_in[5], (const float*)d_in[11], (const float*)d_in[17]};
    const float* c_g[3] = {(const float*)d_in[6], (const float*)d_in[12], (const float*)d_in[18]};
    const float* c_be[3] = {(const float*)d_in[7], (const float*)d_in[13], (const float*)d_in[19]};
    const float* c_w2[3] = {(const float*)d_in[8], (const float*)d_in[14], (const float*)d_in[20]};
    const float* c_b2[3] = {(const float*)d_in[9], (const float*)d_in[15], (const float*)d_in[21]};
    const float* lin1_w = (const float*)d_in[22];
    const float* lin1_b = (const float*)d_in[23];
    const float* lin2_w = (const float*)d_in[24];
    const float* lin2_b = (const float*)d_in[25];
    float* out = (float*)d_out;

    const int NT[3] = {123904, 11264, 1024};

    char* base = (char*)d_ws;
    size_t off = 0;
    auto take = [&](size_t bytes) -> char* {
        char* p = base + off;
        off = (off + bytes + 255) & ~(size_t)255;
        return p;
    };
    f16* w1t[3];
    w1t[0] = (f16*)take((size_t)256 * 128 * sizeof(f16));
    w1t[1] = (f16*)take((size_t)256 * 256 * sizeof(f16));
    w1t[2] = (f16*)take((size_t)256 * 256 * sizeof(f16));
    f16* w2t[3];
    for (int i = 0; i < 3; ++i) w2t[i] = (f16*)take((size_t)256 * 256 * sizeof(f16));
    f16* lin1t = (f16*)take((size_t)256 * 256 * sizeof(f16));
    float* lin2t_ = (float*)take((size_t)47 * 256 * sizeof(float));
    float* stats = (float*)take(1024 * sizeof(float));
    int* deg = (int*)take((size_t)123904 * sizeof(int));
    int* adj = (int*)take((size_t)123904 * 64 * sizeof(int));
    f16* h0 = (f16*)take((size_t)123904 * 128 * sizeof(f16));  // also holds 11264x256, 1024x256
    f16* h1 = (f16*)take((size_t)123904 * 256 * sizeof(f16));
    f16* X1 = (f16*)take((size_t)123904 * 256 * sizeof(f16));
    f16* X2 = (f16*)take((size_t)11264 * 256 * sizeof(f16));
    f16* X3 = (f16*)take((size_t)1024 * 256 * sizeof(f16));
    f16* T = (f16*)take((size_t)1024 * 256 * sizeof(f16));
    (void)ws_size;
    (void)out_size;
    (void)n_in;

    // weight conversion (tiny)
    wcvt<<<(128 * 256 + 255) / 256, 256, 0, stream>>>(c_w1[0], w1t[0], 128, 256);
    wcvt<<<256, 256, 0, stream>>>(c_w1[1], w1t[1], 256, 256);
    wcvt<<<256, 256, 0, stream>>>(c_w1[2], w1t[2], 256, 256);
    for (int i = 0; i < 3; ++i) wcvt<<<256, 256, 0, stream>>>(c_w2[i], w2t[i], 256, 256);
    wcvt<<<256, 256, 0, stream>>>(lin1_w, lin1t, 256, 256);
    lin2t_k<<<47, 256, 0, stream>>>(lin2_w, lin2t_);

    auto build_adj = [&](int layer, int nt) {
        zero_i32<<<(nt + 255) / 256, 256, 0, stream>>>(deg, nt);
        fill_adj<<<(E[layer] + 255) / 256, 256, 0, stream>>>(ei[layer], ei[layer] + E[layer], deg,
                                                            adj, E[layer]);
    };

    auto run_post = [&](const f16* w1tp, const float* b1, const float* g, const float* be,
                        const f16* w2tp, const float* b2, f16* Xout, int nt, int K1) {
        gemm_bt<false><<<dim3(nt / 64, 4), 256, 0, stream>>>(h0, w1tp, b1, h1, nt, 256, K1);
        zero_stats<<<2, 256, 0, stream>>>(stats);
        colstats<<<(nt + 255) / 256, 256, 0, stream>>>(h1, nt, stats, stats + 256);
        bn_finalize<<<1, 256, 0, stream>>>(stats, stats + 256, g, be, 1.0f / nt, stats + 512,
                                           stats + 768);
        bn_apply<<<(nt * 256 / 8 + 255) / 256, 256, 0, stream>>>(h1, nt * 256 / 8, stats + 512,
                                                                 stats + 768);
        gemm_bt<true><<<dim3(nt / 64, 4), 256, 0, stream>>>(h1, w2tp, b2, Xout, nt, 256, 256);
    };

    // ---- layer 0 (x: fp32, din=128) ----
    build_adj(0, NT[0]);
    gather128<<<NT[0] / 4, 256, 0, stream>>>(x0, deg, adj, h0);
    run_post(w1t[0], c_b1[0], c_g[0], c_be[0], w2t[0], c_b2[0], X1, NT[0], 128);

    // ---- layer 1 (x: X1 f16, din=256) ----
    build_adj(1, NT[1]);
    gather256<<<NT[1] / 4, 256, 0, stream>>>(X1, deg, adj, h0);
    run_post(w1t[1], c_b1[1], c_g[1], c_be[1], w2t[1], c_b2[1], X2, NT[1], 256);

    // ---- layer 2 (x: X2 f16, din=256) ----
    build_adj(2, NT[2]);
    gather256<<<NT[2] / 4, 256, 0, stream>>>(X2, deg, adj, h0);
    run_post(w1t[2], c_b1[2], c_g[2], c_be[2], w2t[2], c_b2[2], X3, NT[2], 256);

    // ---- head ----
    gemm_bt<true><<<dim3(16, 4), 256, 0, stream>>>(X3, lin1t, lin1_b, T, 1024, 256, 256);
    head2<<<1024, 64, 0, stream>>>(T, lin2t_, lin2_b, out, 1024);
}